// Round 1
// baseline (13171.362 us; speedup 1.0000x reference)
//
#include <hip/hip_runtime.h>
#include <cstddef>

#define B_    256
#define TSUB  192
#define SEQ_  128
#define D_    768
#define H_    256
#define G_    1024   // 4*H
#define DH_   512    // 2*H

__device__ __forceinline__ float sigmoidf_(float x) { return 1.0f / (1.0f + __expf(-x)); }

// ---------------------------------------------------------------------------
// Kernel 1: scatter-average.  One block per batch element.
// word_ids are sorted ascending (invalid <0 first); compute per-slot ranges
// via counting, then average each slot's embedding rows.
// ---------------------------------------------------------------------------
__global__ __launch_bounds__(256) void scatter_avg_kernel(
    const float* __restrict__ emb, const int* __restrict__ wid,
    float* __restrict__ avg)
{
    const int b   = blockIdx.x;
    const int tid = threadIdx.x;
    __shared__ int s_wid[TSUB];
    __shared__ int s_start[SEQ_ + 1];

    for (int i = tid; i < TSUB; i += 256) s_wid[i] = wid[b * TSUB + i];
    __syncthreads();
    // s_start[s] = #entries with wid < s  (invalids (<0) land before slot 0)
    for (int s = tid; s <= SEQ_; s += 256) {
        int cnt = 0;
        for (int t = 0; t < TSUB; ++t) cnt += (s_wid[t] < s) ? 1 : 0;
        s_start[s] = cnt;
    }
    __syncthreads();

    const float* eb = emb + (size_t)b * TSUB * D_;
    float*       ab = avg + (size_t)b * SEQ_ * D_;
    for (int s = 0; s < SEQ_; ++s) {
        const int st = s_start[s], en = s_start[s + 1];
        const float inv = (en > st) ? 1.0f / (float)(en - st) : 0.0f;
        for (int d = tid; d < D_; d += 256) {
            float sum = 0.0f;
            for (int t = st; t < en; ++t) sum += eb[(size_t)t * D_ + d];
            ab[(size_t)s * D_ + d] = sum * inv;
        }
    }
}

// ---------------------------------------------------------------------------
// Kernel 2: transpose the four w_hh (1024x256) -> whhT (256x1024) so the
// recurrence can stream k-tiles with coalesced loads.
// ---------------------------------------------------------------------------
__global__ __launch_bounds__(256) void transpose_whh_kernel(
    const float* __restrict__ w0, const float* __restrict__ w1,
    const float* __restrict__ w2, const float* __restrict__ w3,
    float* __restrict__ out)
{
    const int idx = blockIdx.x * 256 + threadIdx.x;   // 4*262144 total
    const int mat = idx >> 18;
    const int r   = idx & 262143;
    const int k   = r >> 10;    // 0..255
    const int n   = r & 1023;   // 0..1023
    const float* w = (mat == 0) ? w0 : (mat == 1) ? w1 : (mat == 2) ? w2 : w3;
    out[idx] = w[n * H_ + k];
}

// ---------------------------------------------------------------------------
// Kernel 3: f32 tiled GEMM  C[M,N] = act( X[M,K] @ W[N,K]^T + bias1 + bias2 )
// 64x64 tile, BK=16, 256 threads, 4x4 per thread.  Simple, correct.
// ---------------------------------------------------------------------------
__global__ __launch_bounds__(256) void gemm_bt_kernel(
    const float* __restrict__ X, const float* __restrict__ W,
    const float* __restrict__ bias1, const float* __restrict__ bias2,
    float* __restrict__ C, int M, int N, int K, int relu)
{
    __shared__ float Xs[16][65];
    __shared__ float Ws[16][65];
    const int m0  = blockIdx.x * 64;
    const int n0  = blockIdx.y * 64;
    const int tid = threadIdx.x;
    const int tx  = tid & 15, ty = tid >> 4;

    float acc[4][4];
#pragma unroll
    for (int i = 0; i < 4; ++i)
#pragma unroll
        for (int j = 0; j < 4; ++j) acc[i][j] = 0.0f;

    for (int k0 = 0; k0 < K; k0 += 16) {
#pragma unroll
        for (int l = 0; l < 4; ++l) {
            const int e = l * 256 + tid;      // 0..1023
            const int r = e >> 4, k = e & 15;
            Xs[k][r] = X[(size_t)(m0 + r) * K + k0 + k];
            Ws[k][r] = W[(size_t)(n0 + r) * K + k0 + k];
        }
        __syncthreads();
#pragma unroll
        for (int kk = 0; kk < 16; ++kk) {
            float a[4], bv[4];
#pragma unroll
            for (int i = 0; i < 4; ++i) a[i] = Xs[kk][ty * 4 + i];
#pragma unroll
            for (int j = 0; j < 4; ++j) bv[j] = Ws[kk][tx * 4 + j];
#pragma unroll
            for (int i = 0; i < 4; ++i)
#pragma unroll
                for (int j = 0; j < 4; ++j) acc[i][j] += a[i] * bv[j];
        }
        __syncthreads();
    }

#pragma unroll
    for (int i = 0; i < 4; ++i) {
        const int m = m0 + ty * 4 + i;
#pragma unroll
        for (int j = 0; j < 4; ++j) {
            const int n = n0 + tx * 4 + j;
            float v = acc[i][j] + bias1[n] + (bias2 ? bias2[n] : 0.0f);
            if (relu) v = fmaxf(v, 0.0f);
            C[(size_t)m * N + n] = v;
        }
    }
}

// ---------------------------------------------------------------------------
// Kernel 4: persistent bidirectional LSTM layer.
// Grid = 64 blocks: dir(2) x batch-group(32), BB=8 batches per block.
// Thread tid owns gate-position k=tid across i,f,g,o -> c state in registers.
// w_hh^T streamed L2->LDS in k-tiles of 8 rows (each 8x1024 f32 = 32 KB).
// No cross-block sync needed: batches are independent.
// ---------------------------------------------------------------------------
#define BB 8
__global__ __launch_bounds__(256) void lstm_kernel(
    const float* __restrict__ xpf, const float* __restrict__ xpb,
    const float* __restrict__ whhT_f, const float* __restrict__ whhT_b,
    float* __restrict__ hout)
{
    const int dir = blockIdx.x >> 5;    // 0 fwd, 1 bwd
    const int grp = blockIdx.x & 31;
    const int tid = threadIdx.x;
    const float* xp   = dir ? xpb : xpf;
    const float* whhT = dir ? whhT_b : whhT_f;
    const int b0 = grp * BB;

    __shared__ float s_h[BB][H_];     // 8 KB
    __shared__ float s_w[8][G_];      // 32 KB k-tile of w_hh^T

    float c_st[BB];
#pragma unroll
    for (int b = 0; b < BB; ++b) { s_h[b][tid] = 0.0f; c_st[b] = 0.0f; }
    __syncthreads();

    for (int step = 0; step < SEQ_; ++step) {
        const int t = dir ? (SEQ_ - 1 - step) : step;
        float g[BB][4];
#pragma unroll
        for (int b = 0; b < BB; ++b) {
            const float* xr = xp + ((size_t)(b0 + b) * SEQ_ + t) * G_;
            g[b][0] = xr[tid];
            g[b][1] = xr[tid + 256];
            g[b][2] = xr[tid + 512];
            g[b][3] = xr[tid + 768];
        }
        for (int kt = 0; kt < H_ / 8; ++kt) {
            __syncthreads();   // previous tile fully consumed
            const float4* src = (const float4*)(whhT + (size_t)kt * 8 * G_);
            float4*       dst = (float4*)&s_w[0][0];
#pragma unroll
            for (int l = 0; l < 8; ++l) dst[l * 256 + tid] = src[l * 256 + tid];
            __syncthreads();
#pragma unroll
            for (int kk = 0; kk < 8; ++kk) {
                const int k = kt * 8 + kk;
                const float w0 = s_w[kk][tid];
                const float w1 = s_w[kk][tid + 256];
                const float w2 = s_w[kk][tid + 512];
                const float w3 = s_w[kk][tid + 768];
#pragma unroll
                for (int b = 0; b < BB; ++b) {
                    const float hv = s_h[b][k];
                    g[b][0] += hv * w0;
                    g[b][1] += hv * w1;
                    g[b][2] += hv * w2;
                    g[b][3] += hv * w3;
                }
            }
        }
        __syncthreads();   // all s_h reads done before overwrite
#pragma unroll
        for (int b = 0; b < BB; ++b) {
            const float iv = sigmoidf_(g[b][0]);
            const float fv = sigmoidf_(g[b][1]);
            const float gv = tanhf(g[b][2]);
            const float ov = sigmoidf_(g[b][3]);
            const float c  = fv * c_st[b] + iv * gv;
            c_st[b] = c;
            const float h = ov * tanhf(c);
            s_h[b][tid] = h;
            hout[((size_t)(b0 + b) * SEQ_ + t) * DH_ + dir * H_ + tid] = h;
        }
        __syncthreads();   // s_h visible for next step
    }
}

// ---------------------------------------------------------------------------
// Kernel 5: final logits.  One wave per (b,t) row; both output classes.
// out layout: (B, 2, SEQ)
// ---------------------------------------------------------------------------
__global__ __launch_bounds__(256) void logits_kernel(
    const float* __restrict__ ff, const float* __restrict__ w_sbd,
    const float* __restrict__ b_sbd, float* __restrict__ out)
{
    const int wave = threadIdx.x >> 6, lane = threadIdx.x & 63;
    const int row  = blockIdx.x * 4 + wave;    // 0..32767
    const int b    = row >> 7, t = row & 127;
    const float* fr = ff + (size_t)row * DH_;
    float a0 = 0.0f, a1 = 0.0f;
    for (int k = lane; k < DH_; k += 64) {
        const float v = fr[k];
        a0 += v * w_sbd[k];
        a1 += v * w_sbd[DH_ + k];
    }
#pragma unroll
    for (int off = 32; off; off >>= 1) {
        a0 += __shfl_down(a0, off);
        a1 += __shfl_down(a1, off);
    }
    if (lane == 0) {
        out[(size_t)b * 2 * SEQ_ + t]        = a0 + b_sbd[0];
        out[(size_t)b * 2 * SEQ_ + SEQ_ + t] = a1 + b_sbd[1];
    }
}

// ---------------------------------------------------------------------------
extern "C" void kernel_launch(void* const* d_in, const int* in_sizes, int n_in,
                              void* d_out, int out_size, void* d_ws, size_t ws_size,
                              hipStream_t stream)
{
    const float* emb   = (const float*)d_in[0];
    const int*   wid   = (const int*)d_in[1];
    const float* w_ih[4] = {(const float*)d_in[2],  (const float*)d_in[6],
                            (const float*)d_in[10], (const float*)d_in[14]};
    const float* w_hh[4] = {(const float*)d_in[3],  (const float*)d_in[7],
                            (const float*)d_in[11], (const float*)d_in[15]};
    const float* b_ih[4] = {(const float*)d_in[4],  (const float*)d_in[8],
                            (const float*)d_in[12], (const float*)d_in[16]};
    const float* b_hh[4] = {(const float*)d_in[5],  (const float*)d_in[9],
                            (const float*)d_in[13], (const float*)d_in[17]};
    const float* w_ff  = (const float*)d_in[18];
    const float* b_ff  = (const float*)d_in[19];
    const float* w_sbd = (const float*)d_in[20];
    const float* b_sbd = (const float*)d_in[21];
    float* out = (float*)d_out;
    float* ws  = (float*)d_ws;

    // Workspace layout (floats).  Region A is time-shared: avg -> h0 -> ff
    // (dataflow-checked: each producer starts only after prior consumer ends).
    const size_t OFF_A   = 0;                         // 25,165,824 (avg) / 16,777,216 (h0, ff)
    const size_t OFF_XPF = 25165824;                  // 33,554,432
    const size_t OFF_XPB = OFF_XPF + 33554432;        // 33,554,432
    const size_t OFF_WT  = OFF_XPB + 33554432;        // 4 * 262,144
    const size_t OFF_H1  = OFF_WT + 4 * 262144;       // 16,777,216
    // total = 110,100,480 floats = 440,401,920 bytes

    float* avg = ws + OFF_A;
    float* h0  = ws + OFF_A;     // reuses avg (avg dead after layer-0 projection)
    float* ffb = ws + OFF_A;     // reuses h0 (h0 dead after layer-1 projection)
    float* xpf = ws + OFF_XPF;
    float* xpb = ws + OFF_XPB;
    float* wT  = ws + OFF_WT;
    float* h1  = ws + OFF_H1;

    const int M = B_ * SEQ_;     // 32768

    // 1) scatter-average
    scatter_avg_kernel<<<B_, 256, 0, stream>>>(emb, wid, avg);

    // 2) w_hh transposes (independent of scatter)
    transpose_whh_kernel<<<4096, 256, 0, stream>>>(w_hh[0], w_hh[1], w_hh[2], w_hh[3], wT);

    // 3) layer-0 input projections  (xp = avg @ w_ih^T + b_ih + b_hh)
    gemm_bt_kernel<<<dim3(M / 64, G_ / 64), 256, 0, stream>>>(
        avg, w_ih[0], b_ih[0], b_hh[0], xpf, M, G_, D_, 0);
    gemm_bt_kernel<<<dim3(M / 64, G_ / 64), 256, 0, stream>>>(
        avg, w_ih[1], b_ih[1], b_hh[1], xpb, M, G_, D_, 0);

    // 4) layer-0 recurrence (both directions) -> h0 (B,SEQ,512)
    lstm_kernel<<<64, 256, 0, stream>>>(xpf, xpb, wT, wT + 262144, h0);

    // 5) layer-1 input projections
    gemm_bt_kernel<<<dim3(M / 64, G_ / 64), 256, 0, stream>>>(
        h0, w_ih[2], b_ih[2], b_hh[2], xpf, M, G_, DH_, 0);
    gemm_bt_kernel<<<dim3(M / 64, G_ / 64), 256, 0, stream>>>(
        h0, w_ih[3], b_ih[3], b_hh[3], xpb, M, G_, DH_, 0);

    // 6) layer-1 recurrence -> h1
    lstm_kernel<<<64, 256, 0, stream>>>(xpf, xpb, wT + 2 * 262144, wT + 3 * 262144, h1);

    // 7) FF (relu)
    gemm_bt_kernel<<<dim3(M / 64, DH_ / 64), 256, 0, stream>>>(
        h1, w_ff, b_ff, nullptr, ffb, M, DH_, DH_, 1);

    // 8) logits -> (B, 2, SEQ)
    logits_kernel<<<M / 4, 256, 0, stream>>>(ffb, w_sbd, b_sbd, out);
}

// Round 2
// 7861.703 us; speedup vs baseline: 1.6754x; 1.6754x over previous
//
#include <hip/hip_runtime.h>
#include <cstddef>

#define B_    256
#define TSUB  192
#define SEQ_  128
#define D_    768
#define H_    256
#define G_    1024   // 4*H
#define DH_   512    // 2*H

__device__ __forceinline__ float sigmoidf_(float x) { return 1.0f / (1.0f + __expf(-x)); }

// ---------------------------------------------------------------------------
// Kernel 1: scatter-average.  One block per batch element.
// ---------------------------------------------------------------------------
__global__ __launch_bounds__(256) void scatter_avg_kernel(
    const float* __restrict__ emb, const int* __restrict__ wid,
    float* __restrict__ avg)
{
    const int b   = blockIdx.x;
    const int tid = threadIdx.x;
    __shared__ int s_wid[TSUB];
    __shared__ int s_start[SEQ_ + 1];

    for (int i = tid; i < TSUB; i += 256) s_wid[i] = wid[b * TSUB + i];
    __syncthreads();
    for (int s = tid; s <= SEQ_; s += 256) {
        int cnt = 0;
        for (int t = 0; t < TSUB; ++t) cnt += (s_wid[t] < s) ? 1 : 0;
        s_start[s] = cnt;
    }
    __syncthreads();

    const float* eb = emb + (size_t)b * TSUB * D_;
    float*       ab = avg + (size_t)b * SEQ_ * D_;
    for (int s = 0; s < SEQ_; ++s) {
        const int st = s_start[s], en = s_start[s + 1];
        const float inv = (en > st) ? 1.0f / (float)(en - st) : 0.0f;
        for (int d = tid; d < D_; d += 256) {
            float sum = 0.0f;
            for (int t = st; t < en; ++t) sum += eb[(size_t)t * D_ + d];
            ab[(size_t)s * D_ + d] = sum * inv;
        }
    }
}

// ---------------------------------------------------------------------------
// Kernel 2: re-layout the four w_hh (1024x256, n=g*256+j major) into
// wT2[k][j][g] so the recurrence reads one float4 (4 gates for hidden j)
// per (k, j) — coalesced L2->register streaming, no LDS staging.
// Reads coalesced, writes scattered (write-combined in L2).
// ---------------------------------------------------------------------------
__global__ __launch_bounds__(256) void transpose_whh_kernel(
    const float* __restrict__ w0, const float* __restrict__ w1,
    const float* __restrict__ w2, const float* __restrict__ w3,
    float* __restrict__ out)
{
    const int idx = blockIdx.x * 256 + threadIdx.x;   // 4*262144 total
    const int mat = idx >> 18;
    const int r   = idx & 262143;
    const int n   = r >> 8;      // 0..1023 (row of w_hh)
    const int k   = r & 255;     // 0..255  (col of w_hh)
    const int g   = n >> 8;      // gate
    const int j   = n & 255;     // hidden unit
    const float* w = (mat == 0) ? w0 : (mat == 1) ? w1 : (mat == 2) ? w2 : w3;
    out[(size_t)mat * 262144 + (k << 10) + (j << 2) + g] = w[r];
}

// ---------------------------------------------------------------------------
// Kernel 3: f32 tiled GEMM  C[M,N] = act( X[M,K] @ W[N,K]^T + bias1 + bias2 )
// ---------------------------------------------------------------------------
__global__ __launch_bounds__(256) void gemm_bt_kernel(
    const float* __restrict__ X, const float* __restrict__ W,
    const float* __restrict__ bias1, const float* __restrict__ bias2,
    float* __restrict__ C, int M, int N, int K, int relu)
{
    __shared__ float Xs[16][65];
    __shared__ float Ws[16][65];
    const int m0  = blockIdx.x * 64;
    const int n0  = blockIdx.y * 64;
    const int tid = threadIdx.x;
    const int tx  = tid & 15, ty = tid >> 4;

    float acc[4][4];
#pragma unroll
    for (int i = 0; i < 4; ++i)
#pragma unroll
        for (int j = 0; j < 4; ++j) acc[i][j] = 0.0f;

    for (int k0 = 0; k0 < K; k0 += 16) {
#pragma unroll
        for (int l = 0; l < 4; ++l) {
            const int e = l * 256 + tid;
            const int r = e >> 4, k = e & 15;
            Xs[k][r] = X[(size_t)(m0 + r) * K + k0 + k];
            Ws[k][r] = W[(size_t)(n0 + r) * K + k0 + k];
        }
        __syncthreads();
#pragma unroll
        for (int kk = 0; kk < 16; ++kk) {
            float a[4], bv[4];
#pragma unroll
            for (int i = 0; i < 4; ++i) a[i] = Xs[kk][ty * 4 + i];
#pragma unroll
            for (int j = 0; j < 4; ++j) bv[j] = Ws[kk][tx * 4 + j];
#pragma unroll
            for (int i = 0; i < 4; ++i)
#pragma unroll
                for (int j = 0; j < 4; ++j) acc[i][j] += a[i] * bv[j];
        }
        __syncthreads();
    }

#pragma unroll
    for (int i = 0; i < 4; ++i) {
        const int m = m0 + ty * 4 + i;
#pragma unroll
        for (int j = 0; j < 4; ++j) {
            const int n = n0 + tx * 4 + j;
            float v = acc[i][j] + bias1[n] + (bias2 ? bias2[n] : 0.0f);
            if (relu) v = fmaxf(v, 0.0f);
            C[(size_t)m * N + n] = v;
        }
    }
}

// ---------------------------------------------------------------------------
// Kernel 4: persistent bidirectional LSTM layer, register-streamed weights.
// Grid = 128 blocks: dir(2) x group(64), BB=4 batches per block.
// Thread tid owns hidden unit j=tid: its 4 gate accumulators (i,f,g,o) for
// all BB batches live in registers; w streamed L2->registers as float4
// (wT2[k][j][4g], coalesced); h broadcast from 4 KB of LDS.
// 2 barriers per step (was 64).  No LDS staging of w (zero intra-step reuse).
// ---------------------------------------------------------------------------
#define BB 4
__global__ __launch_bounds__(256) void lstm_kernel(
    const float* __restrict__ xpf, const float* __restrict__ xpb,
    const float* __restrict__ wf2, const float* __restrict__ wb2,
    float* __restrict__ hout)
{
    const int dir = blockIdx.x >> 6;    // 0 fwd, 1 bwd
    const int grp = blockIdx.x & 63;
    const int tid = threadIdx.x;        // hidden unit j
    const float* xp = dir ? xpb : xpf;
    const float* w2 = dir ? wb2 : wf2;  // [k][j][g]
    const int b0 = grp * BB;

    __shared__ float s_h[BB][H_];       // 4 KB

    float c_st[BB];
#pragma unroll
    for (int b = 0; b < BB; ++b) { s_h[b][tid] = 0.0f; c_st[b] = 0.0f; }
    __syncthreads();

    const float* wrow = w2 + (tid << 2);   // + k*1024

    for (int step = 0; step < SEQ_; ++step) {
        const int t = dir ? (SEQ_ - 1 - step) : step;

        float acc[BB][4];
#pragma unroll
        for (int b = 0; b < BB; ++b) {
            const float* xr = xp + ((size_t)(b0 + b) * SEQ_ + t) * G_;
            acc[b][0] = xr[tid];
            acc[b][1] = xr[tid + 256];
            acc[b][2] = xr[tid + 512];
            acc[b][3] = xr[tid + 768];
        }

#pragma unroll 2
        for (int k0 = 0; k0 < H_; k0 += 4) {
            float4 wv[4];
#pragma unroll
            for (int kk = 0; kk < 4; ++kk)
                wv[kk] = *(const float4*)(wrow + (size_t)(k0 + kk) * G_);
            float4 hv[BB];
#pragma unroll
            for (int b = 0; b < BB; ++b)
                hv[b] = *(const float4*)&s_h[b][k0];
#pragma unroll
            for (int kk = 0; kk < 4; ++kk) {
#pragma unroll
                for (int b = 0; b < BB; ++b) {
                    const float h = ((const float*)&hv[b])[kk];
                    acc[b][0] += wv[kk].x * h;
                    acc[b][1] += wv[kk].y * h;
                    acc[b][2] += wv[kk].z * h;
                    acc[b][3] += wv[kk].w * h;
                }
            }
        }

        __syncthreads();   // all s_h reads done before overwrite
#pragma unroll
        for (int b = 0; b < BB; ++b) {
            const float iv = sigmoidf_(acc[b][0]);
            const float fv = sigmoidf_(acc[b][1]);
            const float gv = tanhf(acc[b][2]);
            const float ov = sigmoidf_(acc[b][3]);
            const float c  = fv * c_st[b] + iv * gv;
            c_st[b] = c;
            const float h = ov * tanhf(c);
            s_h[b][tid] = h;
            hout[((size_t)(b0 + b) * SEQ_ + t) * DH_ + dir * H_ + tid] = h;
        }
        __syncthreads();   // new h visible for next step
    }
}

// ---------------------------------------------------------------------------
// Kernel 5: final logits.  out layout: (B, 2, SEQ)
// ---------------------------------------------------------------------------
__global__ __launch_bounds__(256) void logits_kernel(
    const float* __restrict__ ff, const float* __restrict__ w_sbd,
    const float* __restrict__ b_sbd, float* __restrict__ out)
{
    const int wave = threadIdx.x >> 6, lane = threadIdx.x & 63;
    const int row  = blockIdx.x * 4 + wave;
    const int b    = row >> 7, t = row & 127;
    const float* fr = ff + (size_t)row * DH_;
    float a0 = 0.0f, a1 = 0.0f;
    for (int k = lane; k < DH_; k += 64) {
        const float v = fr[k];
        a0 += v * w_sbd[k];
        a1 += v * w_sbd[DH_ + k];
    }
#pragma unroll
    for (int off = 32; off; off >>= 1) {
        a0 += __shfl_down(a0, off);
        a1 += __shfl_down(a1, off);
    }
    if (lane == 0) {
        out[(size_t)b * 2 * SEQ_ + t]        = a0 + b_sbd[0];
        out[(size_t)b * 2 * SEQ_ + SEQ_ + t] = a1 + b_sbd[1];
    }
}

// ---------------------------------------------------------------------------
extern "C" void kernel_launch(void* const* d_in, const int* in_sizes, int n_in,
                              void* d_out, int out_size, void* d_ws, size_t ws_size,
                              hipStream_t stream)
{
    const float* emb   = (const float*)d_in[0];
    const int*   wid   = (const int*)d_in[1];
    const float* w_ih[4] = {(const float*)d_in[2],  (const float*)d_in[6],
                            (const float*)d_in[10], (const float*)d_in[14]};
    const float* w_hh[4] = {(const float*)d_in[3],  (const float*)d_in[7],
                            (const float*)d_in[11], (const float*)d_in[15]};
    const float* b_ih[4] = {(const float*)d_in[4],  (const float*)d_in[8],
                            (const float*)d_in[12], (const float*)d_in[16]};
    const float* b_hh[4] = {(const float*)d_in[5],  (const float*)d_in[9],
                            (const float*)d_in[13], (const float*)d_in[17]};
    const float* w_ff  = (const float*)d_in[18];
    const float* b_ff  = (const float*)d_in[19];
    const float* w_sbd = (const float*)d_in[20];
    const float* b_sbd = (const float*)d_in[21];
    float* out = (float*)d_out;
    float* ws  = (float*)d_ws;

    const size_t OFF_A   = 0;
    const size_t OFF_XPF = 25165824;
    const size_t OFF_XPB = OFF_XPF + 33554432;
    const size_t OFF_WT  = OFF_XPB + 33554432;
    const size_t OFF_H1  = OFF_WT + 4 * 262144;

    float* avg = ws + OFF_A;
    float* h0  = ws + OFF_A;
    float* ffb = ws + OFF_A;
    float* xpf = ws + OFF_XPF;
    float* xpb = ws + OFF_XPB;
    float* wT  = ws + OFF_WT;
    float* h1  = ws + OFF_H1;

    const int M = B_ * SEQ_;

    scatter_avg_kernel<<<B_, 256, 0, stream>>>(emb, wid, avg);
    transpose_whh_kernel<<<4096, 256, 0, stream>>>(w_hh[0], w_hh[1], w_hh[2], w_hh[3], wT);

    gemm_bt_kernel<<<dim3(M / 64, G_ / 64), 256, 0, stream>>>(
        avg, w_ih[0], b_ih[0], b_hh[0], xpf, M, G_, D_, 0);
    gemm_bt_kernel<<<dim3(M / 64, G_ / 64), 256, 0, stream>>>(
        avg, w_ih[1], b_ih[1], b_hh[1], xpb, M, G_, D_, 0);

    lstm_kernel<<<128, 256, 0, stream>>>(xpf, xpb, wT, wT + 262144, h0);

    gemm_bt_kernel<<<dim3(M / 64, G_ / 64), 256, 0, stream>>>(
        h0, w_ih[2], b_ih[2], b_hh[2], xpf, M, G_, DH_, 0);
    gemm_bt_kernel<<<dim3(M / 64, G_ / 64), 256, 0, stream>>>(
        h0, w_ih[3], b_ih[3], b_hh[3], xpb, M, G_, DH_, 0);

    lstm_kernel<<<128, 256, 0, stream>>>(xpf, xpb, wT + 2 * 262144, wT + 3 * 262144, h1);

    gemm_bt_kernel<<<dim3(M / 64, DH_ / 64), 256, 0, stream>>>(
        h1, w_ff, b_ff, nullptr, ffb, M, DH_, DH_, 1);

    logits_kernel<<<M / 4, 256, 0, stream>>>(ffb, w_sbd, b_sbd, out);
}